// Round 7
// baseline (162.348 us; speedup 1.0000x reference)
//
#include <hip/hip_runtime.h>
#include <hip/hip_fp16.h>

#define B_   2
#define T_   256
#define P_   12
#define C_   512
#define H_   8
#define HKV_ 2
#define D_   64
#define S_   (T_ * P_)   // 3072
#define M_   (B_ * S_)   // 6144
#define NQKV 768         // 512 q + 128 k + 128 v

typedef _Float16 half8_t __attribute__((ext_vector_type(8)));
typedef _Float16 half4_t __attribute__((ext_vector_type(4)));
typedef _Float16 half2_t __attribute__((ext_vector_type(2)));
typedef float    float4_t __attribute__((ext_vector_type(4)));

#if __has_builtin(__builtin_amdgcn_exp2f)
#define EXP2(x) __builtin_amdgcn_exp2f(x)
#else
#define EXP2(x) __expf((x) * 0.69314718f)
#endif

#define SOFT_SHIFT 20.0f
#define SOFT_CLAMP2 15.5f
#define QSCALE (0.125f * 1.44269504f)

// direct global -> LDS, 16B per lane; LDS dest = wave-uniform base + lane*16
#define GLDS16(gp, lp)                                                          \
    __builtin_amdgcn_global_load_lds(                                           \
        (const __attribute__((address_space(1))) void*)(gp),                    \
        (__attribute__((address_space(3))) void*)(lp), 16, 0, 0)

// ---------------------------------------------------------------------------
// Kernel 0: prep — cast hs to f16; build transposed f16 weights
// ---------------------------------------------------------------------------
__global__ __launch_bounds__(256) void prep_kernel(
    const float* __restrict__ hs,
    const float* __restrict__ Wq, const float* __restrict__ Wk,
    const float* __restrict__ Wv, const float* __restrict__ Wo,
    _Float16* __restrict__ hs16,      // [M][512]
    _Float16* __restrict__ wcatT,     // [768][512]
    _Float16* __restrict__ woT)       // [512][512]
{
    const int blk = blockIdx.x;
    const int tid = threadIdx.x;

    if (blk < 160) {
        __shared__ __attribute__((aligned(16))) _Float16 Ts[64][72];
        int t, K;
        const float* src; int srcN, col0; _Float16* dst;
        if (blk < 96) { t = blk; K = 512; dst = wcatT;
            int nt = t / 8;
            int kt = t % 8;
            int n0 = nt * 64, k0 = kt * 64;
            if (n0 < 512)      { src = Wq; srcN = 512; col0 = n0; }
            else if (n0 < 640) { src = Wk; srcN = 128; col0 = n0 - 512; }
            else               { src = Wv; srcN = 128; col0 = n0 - 640; }
#pragma unroll
            for (int i = 0; i < 4; ++i) {
                int row = i * 16 + (tid >> 4);
                int cg  = tid & 15;
                float4_t v = *(const float4_t*)(src + (size_t)(k0 + row) * srcN + col0 + cg * 4);
                Ts[cg * 4 + 0][row] = (_Float16)v[0];
                Ts[cg * 4 + 1][row] = (_Float16)v[1];
                Ts[cg * 4 + 2][row] = (_Float16)v[2];
                Ts[cg * 4 + 3][row] = (_Float16)v[3];
            }
            __syncthreads();
#pragma unroll
            for (int i = 0; i < 2; ++i) {
                int seg = i * 256 + tid;
                int row = seg >> 3, s = seg & 7;
                *(half8_t*)(dst + (size_t)(n0 + row) * K + k0 + s * 8) =
                    *(const half8_t*)&Ts[row][s * 8];
            }
        } else { t = blk - 96; K = 512; dst = woT;
            int nt = t / 8, kt = t % 8;
            int n0 = nt * 64, k0 = kt * 64;
#pragma unroll
            for (int i = 0; i < 4; ++i) {
                int row = i * 16 + (tid >> 4);
                int cg  = tid & 15;
                float4_t v = *(const float4_t*)(Wo + (size_t)(k0 + row) * 512 + n0 + cg * 4);
                Ts[cg * 4 + 0][row] = (_Float16)v[0];
                Ts[cg * 4 + 1][row] = (_Float16)v[1];
                Ts[cg * 4 + 2][row] = (_Float16)v[2];
                Ts[cg * 4 + 3][row] = (_Float16)v[3];
            }
            __syncthreads();
#pragma unroll
            for (int i = 0; i < 2; ++i) {
                int seg = i * 256 + tid;
                int row = seg >> 3, s = seg & 7;
                *(half8_t*)(dst + (size_t)(n0 + row) * K + k0 + s * 8) =
                    *(const half8_t*)&Ts[row][s * 8];
            }
        }
    } else {
        int base = (blk - 160) * 4096;
#pragma unroll
        for (int i = 0; i < 16; ++i) {
            int f4 = base + i * 256 + tid;
            float4_t v = *(const float4_t*)(hs + (size_t)f4 * 4);
            half4_t hv;
            hv[0] = (_Float16)v[0]; hv[1] = (_Float16)v[1];
            hv[2] = (_Float16)v[2]; hv[3] = (_Float16)v[3];
            *(half4_t*)(hs16 + (size_t)f4 * 4) = hv;
        }
    }
}

// ---------------------------------------------------------------------------
// Kernel 1: fused QKV GEMM, m97-style 2-phase DMA pipeline.
// Double-buffered linear [64][64] A/B tiles staged via global_load_lds
// (no ds_writes, no staging VGPRs). Bank swizzle folded into the global
// source granule (g ^ (row&7)) and the ds_read column (same XOR), so the
// linear DMA dest still yields conflict-free reads. One vmcnt(0)+barrier
// per k-step, drained AFTER a full k-step of compute (latency hidden).
// ---------------------------------------------------------------------------
__global__ __launch_bounds__(256) void qkv_kernel(
    const _Float16* __restrict__ A,      // [M][512]
    const _Float16* __restrict__ WT,     // [768][512]
    const float* __restrict__ pitch,     // [128][64]
    _Float16* __restrict__ qb,           // [B][8][S][64]
    _Float16* __restrict__ kb,           // [B][2][S][64]
    _Float16* __restrict__ vb)           // [B][2][64][S]
{
    const int m0   = blockIdx.x * 64;
    const int n0   = blockIdx.y * 64;
    const int tid  = threadIdx.x;
    const int wave = tid >> 6;
    const int lane = tid & 63;
    const int ln   = lane & 15;
    const int quad = lane >> 4;

    // gs: A0 | A1 | B0 | B1, each 4096 halves (8KB). total 32KB.
    __shared__ __attribute__((aligned(16))) _Float16 gs[16384];

    float4_t acc[4];
#pragma unroll
    for (int nt = 0; nt < 4; ++nt) acc[nt] = (float4_t){0.f, 0.f, 0.f, 0.f};

    // DMA geometry: instr covers 64 granules (16B) = 8 rows x 8 granules.
    // lane -> row = 8*wave + (lane>>3) (+32 for 2nd instr), g = lane&7.
    // source granule pre-swizzled: g ^ (row&7); row&7 == lane>>3 here.
    const int srow = wave * 8 + (lane >> 3);
    const int sg   = (lane & 7) ^ (lane >> 3);
    const _Float16* Asrc = A  + (size_t)(m0 + srow) * 512 + sg * 8;
    const _Float16* Bsrc = WT + (size_t)(n0 + srow) * 512 + sg * 8;
    _Float16* const awd = gs + wave * 512;           // A dest (wave-uniform)
    _Float16* const bwd = gs + 8192 + wave * 512;    // B dest

#define QKV_STAGE(buf, k0)                                        \
    do {                                                          \
        GLDS16(Asrc + (k0),         awd + (buf) * 4096);          \
        GLDS16(Asrc + (k0) + 16384, awd + (buf) * 4096 + 2048);   \
        GLDS16(Bsrc + (k0),         bwd + (buf) * 4096);          \
        GLDS16(Bsrc + (k0) + 16384, bwd + (buf) * 4096 + 2048);   \
    } while (0)

    const int colx = (ln & 7) << 3;   // read-side granule XOR (halves)

    QKV_STAGE(0, 0);
    asm volatile("s_waitcnt vmcnt(0)" ::: "memory");
    __syncthreads();

#pragma unroll
    for (int kk = 0; kk < 8; ++kk) {
        const int cur = kk & 1;
        if (kk < 7) QKV_STAGE(cur ^ 1, (kk + 1) * 64);

#pragma unroll
        for (int ks = 0; ks < 2; ++ks) {
            half8_t afrag = *(const half8_t*)&gs[cur * 4096 +
                (wave * 16 + ln) * 64 + ((ks * 32 + quad * 8) ^ colx)];
#pragma unroll
            for (int nt = 0; nt < 4; ++nt) {
                half8_t bfrag = *(const half8_t*)&gs[8192 + cur * 4096 +
                    (nt * 16 + ln) * 64 + ((ks * 32 + quad * 8) ^ colx)];
                acc[nt] = __builtin_amdgcn_mfma_f32_16x16x32_f16(afrag, bfrag, acc[nt], 0, 0, 0);
            }
        }

        if (kk < 7) {
            asm volatile("s_waitcnt vmcnt(0)" ::: "memory");
            __syncthreads();
        }
    }
#undef QKV_STAGE

    // epilogue (R4-proven): single mod per thread, incremental p wrap
    const int bb      = m0 / S_;
    const int s00     = m0 - bb * S_;
    const int sl_base = wave * 16 + quad * 4;
    const int s_base  = s00 + sl_base;
    const int p_base  = s_base % P_;

    if (n0 < 512) {
        const int h = n0 >> 6;
#pragma unroll
        for (int r = 0; r < 4; ++r) {
            int p = p_base + r; if (p >= P_) p -= P_;
            const float* pr = pitch + p * 64;
            size_t rowb = ((size_t)(bb * H_ + h) * S_ + s_base + r) * 64;
#pragma unroll
            for (int nt = 0; nt < 4; ++nt) {
                int dd = nt * 16 + ln;
                float v = (acc[nt][r] + pr[dd]) * QSCALE;
                qb[rowb + dd] = (_Float16)v;
            }
        }
    } else if (n0 < 640) {
        const int h = (n0 - 512) >> 6;
#pragma unroll
        for (int r = 0; r < 4; ++r) {
            int p = p_base + r; if (p >= P_) p -= P_;
            const float* pr = pitch + p * 64;
            size_t rowb = ((size_t)(bb * HKV_ + h) * S_ + s_base + r) * 64;
#pragma unroll
            for (int nt = 0; nt < 4; ++nt) {
                int dd = nt * 16 + ln;
                kb[rowb + dd] = (_Float16)(acc[nt][r] + pr[dd]);
            }
        }
    } else {
        // V region: transpose 64s x 64d through gs[0..4095] ([64][64] + XOR),
        // then coalesced 16B row stores. XOR keeps writes 2-way, reads optimal.
        const int h = (n0 - 640) >> 6;
        __syncthreads();
#pragma unroll
        for (int nt = 0; nt < 4; ++nt)
#pragma unroll
            for (int r = 0; r < 4; ++r)
                gs[(nt * 16 + ln) * 64 + ((sl_base + r) ^ ((ln & 7) << 3))] =
                    (_Float16)acc[nt][r];
        __syncthreads();
        const int rw = tid >> 2;
        const int c0 = (tid & 3) * 16;
        const int rx = (rw & 7) << 3;
        _Float16* dst = vb + ((size_t)(bb * HKV_ + h) * 64 + rw) * S_ + s00 + c0;
        *(half8_t*)dst       = *(const half8_t*)&gs[rw * 64 + (c0 ^ rx)];
        *(half8_t*)(dst + 8) = *(const half8_t*)&gs[rw * 64 + ((c0 + 8) ^ rx)];
    }
}

// ---------------------------------------------------------------------------
// Kernel 2: flash attention — Round-2 main loop (best measured: 69.9 us,
// occ 47%, LDS 48128 = 3 blocks/CU) + Round-4's bank-clean combine
// (stride-20 od in Ks region, float4 l in Ps region).
// 8 waves, 128-key tiles; wave w: queries (w&3)*16, keys (w>>2)*32 of each
// 64-key half. Register-prefetch staging (latency hidden under compute).
// ---------------------------------------------------------------------------
__global__ __launch_bounds__(512) void attn_kernel(
    const _Float16* __restrict__ qbuf,  // [B][H][S][64]
    const _Float16* __restrict__ kbuf,  // [B][HKV][S][64]
    const _Float16* __restrict__ vtb,   // [B][HKV][64][S]
    _Float16* __restrict__ ob)          // [B*S][512]
{
    const int qblk = blockIdx.x;
    const int bh   = blockIdx.y;
    const int b    = bh >> 3;
    const int h    = bh & 7;
    const int hkv  = h >> 2;
    const int tid  = threadIdx.x;
    const int w    = tid >> 6;          // 0..7
    const int lane = tid & 63;
    const int ln   = lane & 15;
    const int quad = lane >> 4;

    const _Float16* Q  = qbuf + ((size_t)(b * H_ + h)) * S_ * 64;
    const _Float16* K  = kbuf + ((size_t)(b * HKV_ + hkv)) * S_ * 64;
    const _Float16* Vt = vtb  + ((size_t)(b * HKV_ + hkv)) * 64 * S_;

    __shared__ __attribute__((aligned(16))) _Float16 Ks[128][80];   // 20480 B
    __shared__ __attribute__((aligned(16))) _Float16 VT[64][136];   // 17408 B
    __shared__ __attribute__((aligned(16))) _Float16 Ps[8][16][40]; // 10240 B

    const int qbase = qblk * 64 + (w & 3) * 16;
    const int kk0   = (w >> 2) * 32;

    half8_t qfrag[2];
#pragma unroll
    for (int ks = 0; ks < 2; ++ks)
        qfrag[ks] = *(const half8_t*)&Q[(size_t)(qbase + ln) * 64 + ks * 32 + quad * 8];

    float4_t o[4];
#pragma unroll
    for (int nt = 0; nt < 4; ++nt) o[nt] = (float4_t){0.f, 0.f, 0.f, 0.f};
    float lr[4] = {0.f, 0.f, 0.f, 0.f};

    // staging: 2 K segs + 2 V segs per thread (512 threads)
    const int j = tid >> 3, s = tid & 7;        // j: 0..63
    // key-interleave swizzle so packed half2 P writes land in natural A-frag
    // order; swz(j+64) = swz(j)+64.
    const int r0 = ((j & 1) << 4) | ((j >> 5) << 5) | ((j >> 1) & 15);

    half8_t kr0, kr1, vr0, vr1;
    kr0 = *(const half8_t*)&K[(size_t)j * 64 + s * 8];
    kr1 = *(const half8_t*)&K[(size_t)(64 + j) * 64 + s * 8];
    vr0 = *(const half8_t*)&Vt[(size_t)j * S_ + s * 8];
    vr1 = *(const half8_t*)&Vt[(size_t)j * S_ + 64 + s * 8];

    for (int kt = 0; kt < S_; kt += 128) {
        __syncthreads();
        *(half8_t*)&Ks[r0][s * 8]      = kr0;
        *(half8_t*)&Ks[r0 + 64][s * 8] = kr1;
        *(half8_t*)&VT[j][s * 8]       = vr0;
        *(half8_t*)&VT[j][64 + s * 8]  = vr1;
        __syncthreads();

        if (kt + 128 < S_) {
            kr0 = *(const half8_t*)&K[(size_t)(kt + 128 + j) * 64 + s * 8];
            kr1 = *(const half8_t*)&K[(size_t)(kt + 128 + 64 + j) * 64 + s * 8];
            vr0 = *(const half8_t*)&Vt[(size_t)j * S_ + kt + 128 + s * 8];
            vr1 = *(const half8_t*)&Vt[(size_t)j * S_ + kt + 128 + 64 + s * 8];
        }

#pragma unroll
        for (int h2 = 0; h2 < 2; ++h2) {
            const int kb = h2 * 64 + kk0;

            // QK^T: this wave's 32 keys of this half (2 interleaved 16-tiles)
            float4_t sf[2];
            __builtin_amdgcn_s_setprio(1);
#pragma unroll
            for (int c = 0; c < 2; ++c) {
                sf[c] = (float4_t){-SOFT_SHIFT, -SOFT_SHIFT, -SOFT_SHIFT, -SOFT_SHIFT};
#pragma unroll
                for (int ks = 0; ks < 2; ++ks) {
                    half8_t kf = *(const half8_t*)&Ks[kb + c * 16 + ln][ks * 32 + quad * 8];
                    sf[c] = __builtin_amdgcn_mfma_f32_16x16x32_f16(qfrag[ks], kf, sf[c], 0, 0, 0);
                }
            }
            __builtin_amdgcn_s_setprio(0);

            // fixed-shift softmax, packed half2 P writes
#pragma unroll
            for (int rr = 0; rr < 4; ++rr) {
                float p0 = EXP2(fminf(sf[0][rr], SOFT_CLAMP2));
                float p1 = EXP2(fminf(sf[1][rr], SOFT_CLAMP2));
                lr[rr] += p0 + p1;
                half2_t w2; w2[0] = (_Float16)p0; w2[1] = (_Float16)p1;
                *(half2_t*)&Ps[w][quad * 4 + rr][2 * ln] = w2;
            }

            // PV: O(16q x 64d) += P(16q x 32k) . V(32k x 64d)
            half8_t pf = *(const half8_t*)&Ps[w][ln][quad * 8];
            __builtin_amdgcn_s_setprio(1);
#pragma unroll
            for (int nt = 0; nt < 4; ++nt) {
                half8_t vf = *(const half8_t*)&VT[nt * 16 + ln][kb + quad * 8];
                o[nt] = __builtin_amdgcn_mfma_f32_16x16x32_f16(pf, vf, o[nt], 0, 0, 0);
            }
            __builtin_amdgcn_s_setprio(0);
        }
    }

    // cross-wave combine: wave w and w+4 share queries, disjoint keys.
    // Bank-clean scratch (R4-proven): o at stride 20, l as one float4/lane.
    __syncthreads();
    if (w >= 4) {
        float* od = (float*)&Ks[0][0] + (w - 4) * 1280;   // 4x1280 = 5120 = Ks
#pragma unroll
        for (int nt = 0; nt < 4; ++nt)
            *(float4_t*)&od[lane * 20 + nt * 4] = o[nt];
        float* ld = (float*)&Ps[0][0][0] + (w - 4) * 256;
        *(float4_t*)&ld[lane * 4] = (float4_t){lr[0], lr[1], lr[2], lr[3]};
    }
    __syncthreads();
    if (w < 4) {
        const float* os = (const float*)&Ks[0][0] + w * 1280;
        const float* ls = (const float*)&Ps[0][0][0] + w * 256;
        float4_t ls4 = *(const float4_t*)&ls[lane * 4];
        float4_t os4[4];
#pragma unroll
        for (int nt = 0; nt < 4; ++nt)
            os4[nt] = *(const float4_t*)&os[lane * 20 + nt * 4];
#pragma unroll
        for (int rr = 0; rr < 4; ++rr) {
            float l = lr[rr] + ls4[rr];
            l += __shfl_xor(l, 1);
            l += __shfl_xor(l, 2);
            l += __shfl_xor(l, 4);
            l += __shfl_xor(l, 8);
            float inv = 1.0f / l;
            int qg = qbase + quad * 4 + rr;
            size_t base = ((size_t)(b * S_ + qg)) * 512 + h * 64;
#pragma unroll
            for (int nt = 0; nt < 4; ++nt) {
                float vsum = o[nt][rr] + os4[nt][rr];
                ob[base + nt * 16 + ln] = (_Float16)(vsum * inv);
            }
        }
    }
}

// ---------------------------------------------------------------------------
// Kernel 3: O(f16, M x 512) @ Wo -> fp32 out. Same 2-phase DMA pipeline.
// ---------------------------------------------------------------------------
__global__ __launch_bounds__(256) void proj_out_kernel(
    const _Float16* __restrict__ A,      // [M][512]
    const _Float16* __restrict__ WT,     // [512][512]
    float* __restrict__ outp)            // [M][512]
{
    const int m0   = blockIdx.x * 64;
    const int n0   = blockIdx.y * 64;
    const int tid  = threadIdx.x;
    const int wave = tid >> 6;
    const int lane = tid & 63;
    const int ln   = lane & 15;
    const int quad = lane >> 4;

    __shared__ __attribute__((aligned(16))) _Float16 gs[16384];

    float4_t acc[4];
#pragma unroll
    for (int nt = 0; nt < 4; ++nt) acc[nt] = (float4_t){0.f, 0.f, 0.f, 0.f};

    const int srow = wave * 8 + (lane >> 3);
    const int sg   = (lane & 7) ^ (lane >> 3);
    const _Float16* Asrc = A  + (size_t)(m0 + srow) * 512 + sg * 8;
    const _Float16* Bsrc = WT + (size_t)(n0 + srow) * 512 + sg * 8;
    _Float16* const awd = gs + wave * 512;
    _Float16* const bwd = gs + 8192 + wave * 512;

#define PRJ_STAGE(buf, k0)                                        \
    do {                                                          \
        GLDS16(Asrc + (k0),         awd + (buf) * 4096);          \
        GLDS16(Asrc + (k0) + 16384, awd + (buf) * 4096 + 2048);   \
        GLDS16(Bsrc + (k0),         bwd + (buf) * 4096);          \
        GLDS16(Bsrc + (k0) + 16384, bwd + (buf) * 4096 + 2048);   \
    } while (0)

    const int colx = (ln & 7) << 3;

    PRJ_STAGE(0, 0);
    asm volatile("s_waitcnt vmcnt(0)" ::: "memory");
    __syncthreads();

#pragma unroll
    for (int kk = 0; kk < 8; ++kk) {
        const int cur = kk & 1;
        if (kk < 7) PRJ_STAGE(cur ^ 1, (kk + 1) * 64);

#pragma unroll
        for (int ks = 0; ks < 2; ++ks) {
            half8_t afrag = *(const half8_t*)&gs[cur * 4096 +
                (wave * 16 + ln) * 64 + ((ks * 32 + quad * 8) ^ colx)];
#pragma unroll
            for (int nt = 0; nt < 4; ++nt) {
                half8_t bfrag = *(const half8_t*)&gs[8192 + cur * 4096 +
                    (nt * 16 + ln) * 64 + ((ks * 32 + quad * 8) ^ colx)];
                acc[nt] = __builtin_amdgcn_mfma_f32_16x16x32_f16(afrag, bfrag, acc[nt], 0, 0, 0);
            }
        }

        if (kk < 7) {
            asm volatile("s_waitcnt vmcnt(0)" ::: "memory");
            __syncthreads();
        }
    }
#undef PRJ_STAGE

#pragma unroll
    for (int nt = 0; nt < 4; ++nt) {
        int n = n0 + nt * 16 + ln;
#pragma unroll
        for (int r = 0; r < 4; ++r) {
            int m = m0 + wave * 16 + quad * 4 + r;
            outp[(size_t)m * 512 + n] = acc[nt][r];
        }
    }
}

// ---------------------------------------------------------------------------
extern "C" void kernel_launch(void* const* d_in, const int* in_sizes, int n_in,
                              void* d_out, int out_size, void* d_ws, size_t ws_size,
                              hipStream_t stream) {
    const float* hs    = (const float*)d_in[0];
    const float* Wq    = (const float*)d_in[1];
    const float* Wk    = (const float*)d_in[2];
    const float* Wv    = (const float*)d_in[3];
    const float* Wo    = (const float*)d_in[4];
    const float* pitch = (const float*)d_in[5];
    float* out = (float*)d_out;

    // ws layout (f16 elements). o_buf aliases hs16 (hs16 dead after qkv_kernel).
    _Float16* hs16  = (_Float16*)d_ws;                           // M*512 = 3,145,728
    _Float16* o_buf = hs16;                                      // alias
    _Float16* q_buf = hs16 + (size_t)M_ * 512;                   // 3,145,728
    _Float16* k_buf = q_buf + (size_t)B_ * H_ * S_ * 64;         //   786,432
    _Float16* v_buf = k_buf + (size_t)B_ * HKV_ * S_ * 64;       //   786,432
    _Float16* wcatT = v_buf + (size_t)B_ * HKV_ * S_ * 64;       //   393,216
    _Float16* woT   = wcatT + (size_t)NQKV * 512;                //   262,144

    prep_kernel<<<352, 256, 0, stream>>>(hs, Wq, Wk, Wv, Wo, hs16, wcatT, woT);
    qkv_kernel<<<dim3(M_ / 64, NQKV / 64), 256, 0, stream>>>(hs16, wcatT, pitch, q_buf, k_buf, v_buf);
    attn_kernel<<<dim3(S_ / 64, B_ * H_), 512, 0, stream>>>(q_buf, k_buf, v_buf, o_buf);
    proj_out_kernel<<<dim3(M_ / 64, 8), 256, 0, stream>>>(o_buf, woT, out);
}

// Round 8
// 158.531 us; speedup vs baseline: 1.0241x; 1.0241x over previous
//
#include <hip/hip_runtime.h>
#include <hip/hip_fp16.h>

#define B_   2
#define T_   256
#define P_   12
#define C_   512
#define H_   8
#define HKV_ 2
#define D_   64
#define S_   (T_ * P_)   // 3072
#define M_   (B_ * S_)   // 6144
#define NQKV 768         // 512 q + 128 k + 128 v

typedef _Float16 half8_t __attribute__((ext_vector_type(8)));
typedef _Float16 half4_t __attribute__((ext_vector_type(4)));
typedef _Float16 half2_t __attribute__((ext_vector_type(2)));
typedef float    float4_t __attribute__((ext_vector_type(4)));

#if __has_builtin(__builtin_amdgcn_exp2f)
#define EXP2(x) __builtin_amdgcn_exp2f(x)
#else
#define EXP2(x) __expf((x) * 0.69314718f)
#endif

#define SOFT_SHIFT 20.0f
#define SOFT_CLAMP2 15.5f
#define QSCALE (0.125f * 1.44269504f)

// direct global -> LDS, 16B per lane; LDS dest = wave-uniform base + lane*16
#define GLDS16(gp, lp)                                                          \
    __builtin_amdgcn_global_load_lds(                                           \
        (const __attribute__((address_space(1))) void*)(gp),                    \
        (__attribute__((address_space(3))) void*)(lp), 16, 0, 0)

__device__ __forceinline__ half8_t cvt8(float4_t u0, float4_t u1) {
    half8_t h;
    h[0] = (_Float16)u0[0]; h[1] = (_Float16)u0[1];
    h[2] = (_Float16)u0[2]; h[3] = (_Float16)u0[3];
    h[4] = (_Float16)u1[0]; h[5] = (_Float16)u1[1];
    h[6] = (_Float16)u1[2]; h[7] = (_Float16)u1[3];
    return h;
}

// ---------------------------------------------------------------------------
// Kernel 0: prep — weights only (hs cast ELIMINATED; qkv reads hs f32).
//   blocks [0,96):   Wcat^T tiles (768 x 512)  [n][k]
//   blocks [96,160): Wo^T tiles   (512 x 512)  [n][k]
// ---------------------------------------------------------------------------
__global__ __launch_bounds__(256) void prep_kernel(
    const float* __restrict__ Wq, const float* __restrict__ Wk,
    const float* __restrict__ Wv, const float* __restrict__ Wo,
    _Float16* __restrict__ wcatT,     // [768][512]
    _Float16* __restrict__ woT)       // [512][512]
{
    const int blk = blockIdx.x;
    const int tid = threadIdx.x;

    __shared__ __attribute__((aligned(16))) _Float16 Ts[64][72];
    if (blk < 96) {
        int nt = blk / 8, kt = blk % 8;
        int n0 = nt * 64, k0 = kt * 64;
        const float* src; int srcN, col0;
        if (n0 < 512)      { src = Wq; srcN = 512; col0 = n0; }
        else if (n0 < 640) { src = Wk; srcN = 128; col0 = n0 - 512; }
        else               { src = Wv; srcN = 128; col0 = n0 - 640; }
#pragma unroll
        for (int i = 0; i < 4; ++i) {
            int row = i * 16 + (tid >> 4);
            int cg  = tid & 15;
            float4_t v = *(const float4_t*)(src + (size_t)(k0 + row) * srcN + col0 + cg * 4);
            Ts[cg * 4 + 0][row] = (_Float16)v[0];
            Ts[cg * 4 + 1][row] = (_Float16)v[1];
            Ts[cg * 4 + 2][row] = (_Float16)v[2];
            Ts[cg * 4 + 3][row] = (_Float16)v[3];
        }
        __syncthreads();
#pragma unroll
        for (int i = 0; i < 2; ++i) {
            int seg = i * 256 + tid;
            int row = seg >> 3, s = seg & 7;
            *(half8_t*)(wcatT + (size_t)(n0 + row) * 512 + k0 + s * 8) =
                *(const half8_t*)&Ts[row][s * 8];
        }
    } else {
        int t = blk - 96;
        int nt = t / 8, kt = t % 8;
        int n0 = nt * 64, k0 = kt * 64;
#pragma unroll
        for (int i = 0; i < 4; ++i) {
            int row = i * 16 + (tid >> 4);
            int cg  = tid & 15;
            float4_t v = *(const float4_t*)(Wo + (size_t)(k0 + row) * 512 + n0 + cg * 4);
            Ts[cg * 4 + 0][row] = (_Float16)v[0];
            Ts[cg * 4 + 1][row] = (_Float16)v[1];
            Ts[cg * 4 + 2][row] = (_Float16)v[2];
            Ts[cg * 4 + 3][row] = (_Float16)v[3];
        }
        __syncthreads();
#pragma unroll
        for (int i = 0; i < 2; ++i) {
            int seg = i * 256 + tid;
            int row = seg >> 3, s = seg & 7;
            *(half8_t*)(woT + (size_t)(n0 + row) * 512 + k0 + s * 8) =
                *(const half8_t*)&Ts[row][s * 8];
        }
    }
}

// ---------------------------------------------------------------------------
// Kernel 1: fused QKV GEMM. hs(f32, M x 512) @ WcatT^T -> q/k/v buffers.
// A staged from f32 via reg-load + cvt + swizzled ds_write (no prep pass!);
// B staged via global_load_lds DMA (pre-swizzled source, linear dest).
// Both use LDS[row][g ^ (row&7)] granule convention; reads XOR (ln&7).
// Double-buffered, one vmcnt(0)+barrier per k-step after a full compute
// step (latency hidden; R7-proven placement).
// ---------------------------------------------------------------------------
__global__ __launch_bounds__(256) void qkv_kernel(
    const float* __restrict__ A32,       // [M][512] f32 (= hs)
    const _Float16* __restrict__ WT,     // [768][512]
    const float* __restrict__ pitch,     // [128][64]
    _Float16* __restrict__ qb,           // [B][8][S][64]
    _Float16* __restrict__ kb,           // [B][2][S][64]
    _Float16* __restrict__ vb)           // [B][2][64][S]
{
    const int m0   = blockIdx.x * 64;
    const int n0   = blockIdx.y * 64;
    const int tid  = threadIdx.x;
    const int wave = tid >> 6;
    const int lane = tid & 63;
    const int ln   = lane & 15;
    const int quad = lane >> 4;

    // gs: A0 | A1 | B0 | B1, each 4096 halves (8KB). total 32KB.
    __shared__ __attribute__((aligned(16))) _Float16 gs[16384];

    float4_t acc[4];
#pragma unroll
    for (int nt = 0; nt < 4; ++nt) acc[nt] = (float4_t){0.f, 0.f, 0.f, 0.f};

    // B DMA geometry (R7-proven): lane -> row = 8*wave + (lane>>3), g = lane&7,
    // source granule pre-swizzled g ^ (row&7).
    const int brow = wave * 8 + (lane >> 3);
    const int bg   = (lane & 7) ^ (lane >> 3);
    const _Float16* Bsrc = WT + (size_t)(n0 + brow) * 512 + bg * 8;
    _Float16* const bwd = gs + 8192 + wave * 512;

#define STAGE_B(buf, k0)                                          \
    do {                                                          \
        GLDS16(Bsrc + (k0),         bwd + (buf) * 4096);          \
        GLDS16(Bsrc + (k0) + 16384, bwd + (buf) * 4096 + 2048);   \
    } while (0)

    // A reg-staging geometry: thread -> rows {asr, asr+32}, col group ass (8 f32).
    const int asr = tid >> 3;          // 0..31
    const int ass = tid & 7;
    const int awz = (ass ^ (asr & 7)) * 8;   // swizzled dest granule (halves)

    const int colx = (ln & 7) << 3;    // read-side granule XOR (halves)

    half8_t ar[2];

    // prologue: stage k-step 0 into buf 0
    STAGE_B(0, 0);
#pragma unroll
    for (int i = 0; i < 2; ++i) {
        const float* p = A32 + (size_t)(m0 + i * 32 + asr) * 512 + ass * 8;
        ar[i] = cvt8(*(const float4_t*)p, *(const float4_t*)(p + 4));
    }
#pragma unroll
    for (int i = 0; i < 2; ++i)
        *(half8_t*)&gs[(i * 32 + asr) * 64 + awz] = ar[i];
    asm volatile("s_waitcnt vmcnt(0)" ::: "memory");
    __syncthreads();

#pragma unroll
    for (int kk = 0; kk < 8; ++kk) {
        const int cur = kk & 1;
        if (kk < 7) {
            STAGE_B(cur ^ 1, (kk + 1) * 64);
#pragma unroll
            for (int i = 0; i < 2; ++i) {
                const float* p = A32 + (size_t)(m0 + i * 32 + asr) * 512 + (kk + 1) * 64 + ass * 8;
                ar[i] = cvt8(*(const float4_t*)p, *(const float4_t*)(p + 4));
            }
        }

#pragma unroll
        for (int ks = 0; ks < 2; ++ks) {
            half8_t afrag = *(const half8_t*)&gs[cur * 4096 +
                (wave * 16 + ln) * 64 + ((ks * 32 + quad * 8) ^ colx)];
#pragma unroll
            for (int nt = 0; nt < 4; ++nt) {
                half8_t bfrag = *(const half8_t*)&gs[8192 + cur * 4096 +
                    (nt * 16 + ln) * 64 + ((ks * 32 + quad * 8) ^ colx)];
                acc[nt] = __builtin_amdgcn_mfma_f32_16x16x32_f16(afrag, bfrag, acc[nt], 0, 0, 0);
            }
        }

        if (kk < 7) {
#pragma unroll
            for (int i = 0; i < 2; ++i)
                *(half8_t*)&gs[(cur ^ 1) * 4096 + (i * 32 + asr) * 64 + awz] = ar[i];
            asm volatile("s_waitcnt vmcnt(0)" ::: "memory");
            __syncthreads();
        }
    }
#undef STAGE_B

    // epilogue (R4-proven): single mod per thread, incremental p wrap
    const int bb      = m0 / S_;
    const int s00     = m0 - bb * S_;
    const int sl_base = wave * 16 + quad * 4;
    const int s_base  = s00 + sl_base;
    const int p_base  = s_base % P_;

    if (n0 < 512) {
        const int h = n0 >> 6;
#pragma unroll
        for (int r = 0; r < 4; ++r) {
            int p = p_base + r; if (p >= P_) p -= P_;
            const float* pr = pitch + p * 64;
            size_t rowb = ((size_t)(bb * H_ + h) * S_ + s_base + r) * 64;
#pragma unroll
            for (int nt = 0; nt < 4; ++nt) {
                int dd = nt * 16 + ln;
                float v = (acc[nt][r] + pr[dd]) * QSCALE;
                qb[rowb + dd] = (_Float16)v;
            }
        }
    } else if (n0 < 640) {
        const int h = (n0 - 512) >> 6;
#pragma unroll
        for (int r = 0; r < 4; ++r) {
            int p = p_base + r; if (p >= P_) p -= P_;
            const float* pr = pitch + p * 64;
            size_t rowb = ((size_t)(bb * HKV_ + h) * S_ + s_base + r) * 64;
#pragma unroll
            for (int nt = 0; nt < 4; ++nt) {
                int dd = nt * 16 + ln;
                kb[rowb + dd] = (_Float16)(acc[nt][r] + pr[dd]);
            }
        }
    } else {
        // V region: transpose 64s x 64d through gs[0..4095] ([64][64] + XOR),
        // then coalesced 16B row stores (R4/R7-proven).
        const int h = (n0 - 640) >> 6;
        __syncthreads();
#pragma unroll
        for (int nt = 0; nt < 4; ++nt)
#pragma unroll
            for (int r = 0; r < 4; ++r)
                gs[(nt * 16 + ln) * 64 + ((sl_base + r) ^ ((ln & 7) << 3))] =
                    (_Float16)acc[nt][r];
        __syncthreads();
        const int rw = tid >> 2;
        const int c0 = (tid & 3) * 16;
        const int rx = (rw & 7) << 3;
        _Float16* dst = vb + ((size_t)(bb * HKV_ + h) * 64 + rw) * S_ + s00 + c0;
        *(half8_t*)dst       = *(const half8_t*)&gs[rw * 64 + (c0 ^ rx)];
        *(half8_t*)(dst + 8) = *(const half8_t*)&gs[rw * 64 + ((c0 + 8) ^ rx)];
    }
}

// ---------------------------------------------------------------------------
// Kernel 2: flash attention — Round-2 kernel VERBATIM (best measured:
// 69.9 us, VGPR 40, occ 47.6, 3 blocks/CU). 8 waves, 128-key tiles;
// wave w: queries (w&3)*16, keys (w>>2)*32 of each 64-key half.
// DO NOT touch the epilogue: hoisting its LDS reads into registers raises
// VGPR 40->56 and crosses an occupancy cliff (24 -> 16 waves/CU, +3 us).
// ---------------------------------------------------------------------------
__global__ __launch_bounds__(512) void attn_kernel(
    const _Float16* __restrict__ qbuf,  // [B][H][S][64]
    const _Float16* __restrict__ kbuf,  // [B][HKV][S][64]
    const _Float16* __restrict__ vtb,   // [B][HKV][64][S]
    _Float16* __restrict__ ob)          // [B*S][512]
{
    const int qblk = blockIdx.x;
    const int bh   = blockIdx.y;
    const int b    = bh >> 3;
    const int h    = bh & 7;
    const int hkv  = h >> 2;
    const int tid  = threadIdx.x;
    const int w    = tid >> 6;          // 0..7
    const int lane = tid & 63;
    const int ln   = lane & 15;
    const int quad = lane >> 4;

    const _Float16* Q  = qbuf + ((size_t)(b * H_ + h)) * S_ * 64;
    const _Float16* K  = kbuf + ((size_t)(b * HKV_ + hkv)) * S_ * 64;
    const _Float16* Vt = vtb  + ((size_t)(b * HKV_ + hkv)) * 64 * S_;

    __shared__ __attribute__((aligned(16))) _Float16 Ks[128][80];   // 20480 B
    __shared__ __attribute__((aligned(16))) _Float16 VT[64][136];   // 17408 B
    __shared__ __attribute__((aligned(16))) _Float16 Ps[8][16][40]; // 10240 B

    const int qbase = qblk * 64 + (w & 3) * 16;
    const int kk0   = (w >> 2) * 32;

    half8_t qfrag[2];
#pragma unroll
    for (int ks = 0; ks < 2; ++ks)
        qfrag[ks] = *(const half8_t*)&Q[(size_t)(qbase + ln) * 64 + ks * 32 + quad * 8];

    float4_t o[4];
#pragma unroll
    for (int nt = 0; nt < 4; ++nt) o[nt] = (float4_t){0.f, 0.f, 0.f, 0.f};
    float lr[4] = {0.f, 0.f, 0.f, 0.f};

    // staging: 2 K segs + 2 V segs per thread (512 threads, 128x64 K / 64x128 V)
    const int j = tid >> 3, s = tid & 7;        // j: 0..63
    // key-interleave swizzle so packed half2 P writes land in natural A-frag order;
    // swz(j+64) = swz(j)+64, so rows 64..127 reuse r0+64.
    const int r0 = ((j & 1) << 4) | ((j >> 5) << 5) | ((j >> 1) & 15);

    half8_t kr0, kr1, vr0, vr1;
    kr0 = *(const half8_t*)&K[(size_t)j * 64 + s * 8];
    kr1 = *(const half8_t*)&K[(size_t)(64 + j) * 64 + s * 8];
    vr0 = *(const half8_t*)&Vt[(size_t)j * S_ + s * 8];
    vr1 = *(const half8_t*)&Vt[(size_t)j * S_ + 64 + s * 8];

    for (int kt = 0; kt < S_; kt += 128) {
        __syncthreads();
        *(half8_t*)&Ks[r0][s * 8]      = kr0;
        *(half8_t*)&Ks[r0 + 64][s * 8] = kr1;
        *(half8_t*)&VT[j][s * 8]       = vr0;
        *(half8_t*)&VT[j][64 + s * 8]  = vr1;
        __syncthreads();

        if (kt + 128 < S_) {
            kr0 = *(const half8_t*)&K[(size_t)(kt + 128 + j) * 64 + s * 8];
            kr1 = *(const half8_t*)&K[(size_t)(kt + 128 + 64 + j) * 64 + s * 8];
            vr0 = *(const half8_t*)&Vt[(size_t)j * S_ + kt + 128 + s * 8];
            vr1 = *(const half8_t*)&Vt[(size_t)j * S_ + kt + 128 + 64 + s * 8];
        }

#pragma unroll
        for (int h2 = 0; h2 < 2; ++h2) {
            const int kb = h2 * 64 + kk0;

            // QK^T: this wave's 32 keys of this half (2 interleaved 16-tiles).
            float4_t sf[2];
            __builtin_amdgcn_s_setprio(1);
#pragma unroll
            for (int c = 0; c < 2; ++c) {
                sf[c] = (float4_t){-SOFT_SHIFT, -SOFT_SHIFT, -SOFT_SHIFT, -SOFT_SHIFT};
#pragma unroll
                for (int ks = 0; ks < 2; ++ks) {
                    half8_t kf = *(const half8_t*)&Ks[kb + c * 16 + ln][ks * 32 + quad * 8];
                    sf[c] = __builtin_amdgcn_mfma_f32_16x16x32_f16(qfrag[ks], kf, sf[c], 0, 0, 0);
                }
            }
            __builtin_amdgcn_s_setprio(0);

            // fixed-shift softmax, packed half2 P writes (cols = natural local key)
#pragma unroll
            for (int rr = 0; rr < 4; ++rr) {
                float p0 = EXP2(fminf(sf[0][rr], SOFT_CLAMP2));
                float p1 = EXP2(fminf(sf[1][rr], SOFT_CLAMP2));
                lr[rr] += p0 + p1;
                half2_t w2; w2[0] = (_Float16)p0; w2[1] = (_Float16)p1;
                *(half2_t*)&Ps[w][quad * 4 + rr][2 * ln] = w2;
            }

            // PV: O(16q x 64d) += P(16q x 32k) . V(32k x 64d)
            half8_t pf = *(const half8_t*)&Ps[w][ln][quad * 8];
            __builtin_amdgcn_s_setprio(1);
#pragma unroll
            for (int nt = 0; nt < 4; ++nt) {
                half8_t vf = *(const half8_t*)&VT[nt * 16 + ln][kb + quad * 8];
                o[nt] = __builtin_amdgcn_mfma_f32_16x16x32_f16(pf, vf, o[nt], 0, 0, 0);
            }
            __builtin_amdgcn_s_setprio(0);
        }
    }

    // cross-wave combine: wave w and w+4 share queries, disjoint keys
    __syncthreads();
    if (w >= 4) {
        // o scratch: all four upper waves fit in Ks (5120 floats >= 4096)
        float* od = (float*)&Ks[0][0] + (w - 4) * 1024;
#pragma unroll
        for (int nt = 0; nt < 4; ++nt)
            *(float4_t*)&od[lane * 16 + nt * 4] = o[nt];
        float* ld = (float*)&Ps[0][0][0] + (w - 4) * 256;
#pragma unroll
        for (int rr = 0; rr < 4; ++rr)
            ld[lane * 4 + rr] = lr[rr];
    }
    __syncthreads();
    if (w < 4) {
        const float* os = (const float*)&Ks[0][0] + w * 1024;
        const float* ls = (const float*)&Ps[0][0][0] + w * 256;
#pragma unroll
        for (int rr = 0; rr < 4; ++rr) {
            float l = lr[rr] + ls[lane * 4 + rr];
            l += __shfl_xor(l, 1);
            l += __shfl_xor(l, 2);
            l += __shfl_xor(l, 4);
            l += __shfl_xor(l, 8);
            float inv = 1.0f / l;
            int qg = qbase + quad * 4 + rr;
            size_t base = ((size_t)(b * S_ + qg)) * 512 + h * 64;
#pragma unroll
            for (int nt = 0; nt < 4; ++nt) {
                float vsum = o[nt][rr] + os[lane * 16 + nt * 4 + rr];
                ob[base + nt * 16 + ln] = (_Float16)(vsum * inv);
            }
        }
    }
}

// ---------------------------------------------------------------------------
// Kernel 3: O(f16, M x 512) @ Wo -> fp32 out. R7 DMA pipeline (verbatim).
// ---------------------------------------------------------------------------
__global__ __launch_bounds__(256) void proj_out_kernel(
    const _Float16* __restrict__ A,      // [M][512]
    const _Float16* __restrict__ WT,     // [512][512]
    float* __restrict__ outp)            // [M][512]
{
    const int m0   = blockIdx.x * 64;
    const int n0   = blockIdx.y * 64;
    const int tid  = threadIdx.x;
    const int wave = tid >> 6;
    const int lane = tid & 63;
    const int ln   = lane & 15;
    const int quad = lane >> 4;

    __shared__ __attribute__((aligned(16))) _Float16 gs[16384];

    float4_t acc[4];
#pragma unroll
    for (int nt = 0; nt < 4; ++nt) acc[nt] = (float4_t){0.f, 0.f, 0.f, 0.f};

    const int srow = wave * 8 + (lane >> 3);
    const int sg   = (lane & 7) ^ (lane >> 3);
    const _Float16* Asrc = A  + (size_t)(m0 + srow) * 512 + sg * 8;
    const _Float16* Bsrc = WT + (size_t)(n0 + srow) * 512 + sg * 8;
    _Float16* const awd = gs + wave * 512;
    _Float16* const bwd = gs + 8192 + wave * 512;

#define PRJ_STAGE(buf, k0)                                        \
    do {                                                          \
        GLDS16(Asrc + (k0),         awd + (buf) * 4096);          \
        GLDS16(Asrc + (k0) + 16384, awd + (buf) * 4096 + 2048);   \
        GLDS16(Bsrc + (k0),         bwd + (buf) * 4096);          \
        GLDS16(Bsrc + (k0) + 16384, bwd + (buf) * 4096 + 2048);   \
    } while (0)

    const int colx = (ln & 7) << 3;

    PRJ_STAGE(0, 0);
    asm volatile("s_waitcnt vmcnt(0)" ::: "memory");
    __syncthreads();

#pragma unroll
    for (int kk = 0; kk < 8; ++kk) {
        const int cur = kk & 1;
        if (kk < 7) PRJ_STAGE(cur ^ 1, (kk + 1) * 64);

#pragma unroll
        for (int ks = 0; ks < 2; ++ks) {
            half8_t afrag = *(const half8_t*)&gs[cur * 4096 +
                (wave * 16 + ln) * 64 + ((ks * 32 + quad * 8) ^ colx)];
#pragma unroll
            for (int nt = 0; nt < 4; ++nt) {
                half8_t bfrag = *(const half8_t*)&gs[8192 + cur * 4096 +
                    (nt * 16 + ln) * 64 + ((ks * 32 + quad * 8) ^ colx)];
                acc[nt] = __builtin_amdgcn_mfma_f32_16x16x32_f16(afrag, bfrag, acc[nt], 0, 0, 0);
            }
        }

        if (kk < 7) {
            asm volatile("s_waitcnt vmcnt(0)" ::: "memory");
            __syncthreads();
        }
    }
#undef PRJ_STAGE

#pragma unroll
    for (int nt = 0; nt < 4; ++nt) {
        int n = n0 + nt * 16 + ln;
#pragma unroll
        for (int r = 0; r < 4; ++r) {
            int m = m0 + wave * 16 + quad * 4 + r;
            outp[(size_t)m * 512 + n] = acc[nt][r];
        }
    }
}

// ---------------------------------------------------------------------------
extern "C" void kernel_launch(void* const* d_in, const int* in_sizes, int n_in,
                              void* d_out, int out_size, void* d_ws, size_t ws_size,
                              hipStream_t stream) {
    const float* hs    = (const float*)d_in[0];
    const float* Wq    = (const float*)d_in[1];
    const float* Wk    = (const float*)d_in[2];
    const float* Wv    = (const float*)d_in[3];
    const float* Wo    = (const float*)d_in[4];
    const float* pitch = (const float*)d_in[5];
    float* out = (float*)d_out;

    // ws layout (f16 elements). No hs16 anymore — qkv reads hs f32 directly.
    _Float16* o_buf = (_Float16*)d_ws;                           // M*512 = 3,145,728
    _Float16* q_buf = o_buf + (size_t)M_ * 512;                  // 3,145,728
    _Float16* k_buf = q_buf + (size_t)B_ * H_ * S_ * 64;         //   786,432
    _Float16* v_buf = k_buf + (size_t)B_ * HKV_ * S_ * 64;       //   786,432
    _Float16* wcatT = v_buf + (size_t)B_ * HKV_ * S_ * 64;       //   393,216
    _Float16* woT   = wcatT + (size_t)NQKV * 512;                //   262,144

    prep_kernel<<<160, 256, 0, stream>>>(Wq, Wk, Wv, Wo, wcatT, woT);
    qkv_kernel<<<dim3(M_ / 64, NQKV / 64), 256, 0, stream>>>(hs, wcatT, pitch, q_buf, k_buf, v_buf);
    attn_kernel<<<dim3(S_ / 64, B_ * H_), 512, 0, stream>>>(q_buf, k_buf, v_buf, o_buf);
    proj_out_kernel<<<dim3(M_ / 64, 8), 256, 0, stream>>>(o_buf, woT, out);
}